// Round 7
// baseline (64.834 us; speedup 1.0000x reference)
//
#include <hip/hip_runtime.h>
#include <hip/hip_bf16.h>

// mIoU loss, histogram formulation, two-stage (no global atomics).
// Ledger:
//  R1: global atomics on 60 addrs -> 313us (serialized far-atomics).
//  R2~R3: plain-RMW vs LDS-atomic histogram identical 42us -> DS op mix
//         not the wall. L3-resident replays same time -> not BW-bound.
//  R4: 4-deep unroll: compiler sank loads (VGPR 28) -> no MLP, 52us.
//  R5: sched_barrier(0): VGPR 36 -> void. R6: keep-alive asm: VGPR 44,
//         37.7us -> still can't hold 16 int4 live; wall barely moved.
//  Counter back-calc: VALU/DS/L1/HBM all ~10% busy. No pipe explains 40us.
//  R7 = ABLATION ROUND (pre-registered): hist kernel UNCHANGED + a probe
//  kernel with identical load structure but pure-VALU consume (no DS, no
//  data-dependent addressing). Per-dispatch rocprof splits load-wall vs
//  consume-wall. Outcome A (probe fast): consume indicted -> restructure
//  consume ordering. Outcome B (probe ~40us): memory path indicted.

#define NB      20
#define BLK     256
#define GRIDH   2048
#define PSTRIDE 64   // padded row per block in workspace (16 int4)

#define KEEP4(v) asm volatile("" :: "v"((v).x), "v"((v).y), "v"((v).z), "v"((v).w) : "memory")

__device__ __forceinline__ void process_pix(int p, int t, unsigned* s_col) {
    // packed fields: bits 0..9 pred_count, 10..19 target_count, 20..29 inter
    unsigned m = (unsigned)(p == t);
    atomicAdd(&s_col[p * BLK], 1u + (m << 20));  // pred count + intersection
    atomicAdd(&s_col[t * BLK], 1u << 10);        // target count
}

__device__ __forceinline__ void process_vec(int4 pv, int4 tv, unsigned* s_col) {
    process_pix(pv.x, tv.x, s_col);
    process_pix(pv.y, tv.y, s_col);
    process_pix(pv.z, tv.z, s_col);
    process_pix(pv.w, tv.w, s_col);
}

__global__ __launch_bounds__(BLK) void miou_hist_kernel(
        const int4* __restrict__ preds, const int4* __restrict__ targs,
        unsigned* __restrict__ partials, int n4) {
    __shared__ unsigned s_hist[NB * BLK];
    const int tid = threadIdx.x;

    #pragma unroll
    for (int c = 0; c < NB; ++c) s_hist[c * BLK + tid] = 0u;
    __syncthreads();

    unsigned* s_col = &s_hist[tid];
    const int stride = gridDim.x * BLK;
    int i = blockIdx.x * BLK + tid;

    if (i + 7 * stride < n4) {
        int4 p0 = preds[i];
        int4 p1 = preds[i + stride];
        int4 p2 = preds[i + 2 * stride];
        int4 p3 = preds[i + 3 * stride];
        int4 p4 = preds[i + 4 * stride];
        int4 p5 = preds[i + 5 * stride];
        int4 p6 = preds[i + 6 * stride];
        int4 p7 = preds[i + 7 * stride];
        int4 t0 = targs[i];
        int4 t1 = targs[i + stride];
        int4 t2 = targs[i + 2 * stride];
        int4 t3 = targs[i + 3 * stride];
        int4 t4 = targs[i + 4 * stride];
        int4 t5 = targs[i + 5 * stride];
        int4 t6 = targs[i + 6 * stride];
        int4 t7 = targs[i + 7 * stride];
        KEEP4(p0); KEEP4(t0);
        KEEP4(p1); KEEP4(t1);
        KEEP4(p2); KEEP4(t2);
        KEEP4(p3); KEEP4(t3);
        KEEP4(p4); KEEP4(t4);
        KEEP4(p5); KEEP4(t5);
        KEEP4(p6); KEEP4(t6);
        KEEP4(p7); KEEP4(t7);
        process_vec(p0, t0, s_col);
        process_vec(p1, t1, s_col);
        process_vec(p2, t2, s_col);
        process_vec(p3, t3, s_col);
        process_vec(p4, t4, s_col);
        process_vec(p5, t5, s_col);
        process_vec(p6, t6, s_col);
        process_vec(p7, t7, s_col);
        i += 8 * stride;
    }
    for (; i < n4; i += stride) {
        int4 pv = preds[i];
        int4 tv = targs[i];
        process_vec(pv, tv, s_col);
    }
    __syncthreads();

    const int wid  = tid >> 6;
    const int lane = tid & 63;
    unsigned* dst = &partials[(size_t)blockIdx.x * PSTRIDE];
    for (int c = wid; c < NB; c += (BLK / 64)) {
        unsigned sp = 0, st = 0, si = 0;
        #pragma unroll
        for (int k = 0; k < BLK / 64; ++k) {
            unsigned v = s_hist[c * BLK + k * 64 + lane];
            sp += v & 1023u;
            st += (v >> 10) & 1023u;
            si += (v >> 20) & 1023u;
        }
        #pragma unroll
        for (int off = 32; off > 0; off >>= 1) {
            sp += __shfl_xor(sp, off);
            st += __shfl_xor(st, off);
            si += __shfl_xor(si, off);
        }
        if (lane == 0) {
            dst[c]          = sp;
            dst[NB + c]     = st;
            dst[2 * NB + c] = si;
        }
    }
}

// ---- Diagnostic probe: IDENTICAL load structure, pure-VALU consume. ----
__device__ __forceinline__ unsigned sum4(int4 v) {
    return (unsigned)v.x + (unsigned)v.y + (unsigned)v.z + (unsigned)v.w;
}

__global__ __launch_bounds__(BLK) void miou_stream_probe(
        const int4* __restrict__ preds, const int4* __restrict__ targs,
        unsigned* __restrict__ sink, int n4) {
    const int tid = threadIdx.x;
    const int stride = gridDim.x * BLK;
    int i = blockIdx.x * BLK + tid;
    unsigned acc = 0;

    if (i + 7 * stride < n4) {
        int4 p0 = preds[i];
        int4 p1 = preds[i + stride];
        int4 p2 = preds[i + 2 * stride];
        int4 p3 = preds[i + 3 * stride];
        int4 p4 = preds[i + 4 * stride];
        int4 p5 = preds[i + 5 * stride];
        int4 p6 = preds[i + 6 * stride];
        int4 p7 = preds[i + 7 * stride];
        int4 t0 = targs[i];
        int4 t1 = targs[i + stride];
        int4 t2 = targs[i + 2 * stride];
        int4 t3 = targs[i + 3 * stride];
        int4 t4 = targs[i + 4 * stride];
        int4 t5 = targs[i + 5 * stride];
        int4 t6 = targs[i + 6 * stride];
        int4 t7 = targs[i + 7 * stride];
        KEEP4(p0); KEEP4(t0);
        KEEP4(p1); KEEP4(t1);
        KEEP4(p2); KEEP4(t2);
        KEEP4(p3); KEEP4(t3);
        KEEP4(p4); KEEP4(t4);
        KEEP4(p5); KEEP4(t5);
        KEEP4(p6); KEEP4(t6);
        KEEP4(p7); KEEP4(t7);
        acc += sum4(p0) + sum4(t0) + sum4(p1) + sum4(t1);
        acc += sum4(p2) + sum4(t2) + sum4(p3) + sum4(t3);
        acc += sum4(p4) + sum4(t4) + sum4(p5) + sum4(t5);
        acc += sum4(p6) + sum4(t6) + sum4(p7) + sum4(t7);
        i += 8 * stride;
    }
    for (; i < n4; i += stride) {
        acc += sum4(preds[i]) + sum4(targs[i]);
    }
    #pragma unroll
    for (int off = 32; off > 0; off >>= 1) acc += __shfl_xor(acc, off);
    if ((tid & 63) == 0)
        sink[blockIdx.x * (BLK / 64) + (tid >> 6)] = acc;
}

// One block, 1024 threads. partials = nblocks rows x 16 int4 (coalesced).
__global__ __launch_bounds__(1024) void miou_reduce_kernel(
        const unsigned* __restrict__ partials, int nblocks,
        const int* __restrict__ nb_ptr, const int* __restrict__ smooth_ptr,
        float* __restrict__ out) {
    __shared__ unsigned s_tot[PSTRIDE];
    if (threadIdx.x < PSTRIDE) s_tot[threadIdx.x] = 0u;
    __syncthreads();

    const int col4 = threadIdx.x & 15;
    const int seg  = threadIdx.x >> 4;
    const int4* p4 = (const int4*)partials;

    unsigned ax = 0, ay = 0, az = 0, aw = 0;
    #pragma unroll 8
    for (int r = seg; r < nblocks; r += 64) {
        int4 v = p4[r * 16 + col4];
        ax += (unsigned)v.x; ay += (unsigned)v.y;
        az += (unsigned)v.z; aw += (unsigned)v.w;
    }
    atomicAdd(&s_tot[col4 * 4 + 0], ax);
    atomicAdd(&s_tot[col4 * 4 + 1], ay);
    atomicAdd(&s_tot[col4 * 4 + 2], az);
    atomicAdd(&s_tot[col4 * 4 + 3], aw);
    __syncthreads();

    if (threadIdx.x == 0) {
        const int   nb = *nb_ptr;
        const float s  = (float)(*smooth_ptr);
        float acc_iou = 0.0f;
        for (int c = 0; c < nb && c < NB; ++c) {
            float pc    = (float)s_tot[c];
            float tc    = (float)s_tot[NB + c];
            float inter = (float)s_tot[2 * NB + c];
            float uni   = pc + tc - inter;
            acc_iou += (inter + s) / (uni + s);
        }
        out[0] = 1.0f - acc_iou / (float)nb;
    }
}

extern "C" void kernel_launch(void* const* d_in, const int* in_sizes, int n_in,
                              void* d_out, int out_size, void* d_ws, size_t ws_size,
                              hipStream_t stream) {
    const int4* preds      = (const int4*)d_in[0];
    const int4* targs      = (const int4*)d_in[1];
    const int*  nb_ptr     = (const int*)d_in[2];
    const int*  smooth_ptr = (const int*)d_in[3];
    float*      out        = (float*)d_out;

    int n  = in_sizes[0];
    int n4 = n >> 2;

    unsigned* partials = (unsigned*)d_ws;

    int grid = GRIDH;
    int max_grid = (n4 + BLK - 1) / BLK;
    if (grid > max_grid) grid = max_grid;
    size_t need_per_block = PSTRIDE * sizeof(unsigned);
    if ((size_t)grid * need_per_block > ws_size)
        grid = (int)(ws_size / need_per_block);

    miou_hist_kernel<<<grid, BLK, 0, stream>>>(preds, targs, partials, n4);

    // Diagnostic probe into a disjoint ws region (after partials).
    size_t partials_bytes = (size_t)grid * need_per_block;
    size_t probe_bytes    = (size_t)grid * (BLK / 64) * sizeof(unsigned);
    if (ws_size >= partials_bytes + probe_bytes) {
        unsigned* sink = (unsigned*)((char*)d_ws + partials_bytes);
        miou_stream_probe<<<grid, BLK, 0, stream>>>(preds, targs, sink, n4);
    }

    miou_reduce_kernel<<<1, 1024, 0, stream>>>(partials, grid, nb_ptr, smooth_ptr, out);
}

// Round 8
// 34.625 us; speedup vs baseline: 1.8724x; 1.8724x over previous
//
#include <hip/hip_runtime.h>
#include <hip/hip_bf16.h>

// mIoU loss, histogram formulation, two-stage (no global atomics).
// Ledger:
//  R1: global atomics on 60 addrs -> 313us (serialized far-atomics).
//  R2~R3: RMW vs LDS-atomic identical 42us -> DS op mix not the wall;
//         L3-resident replays same time -> not BW-bound.
//  R4~R6: three VGPR-liveness idioms (unroll / sched_barrier / keep-alive
//         asm) all failed to materialize MLP (VGPR 28/36/44, need 64+).
//  R7 ablation: pure-VALU-consume probe with same loads ~27us vs hist
//         ~35us -> LOAD PATH indicted; ~3 loads outstanding per CU
//         (Little's law). Register allocator defeats ILP at source level.
//  R8: global_load_lds DMA pipeline (m97-proven). Wave-private LDS slots,
//      double-buffered, hand-counted s_waitcnt vmcnt(2) (never 0 in loop),
//      lgkmcnt(0) before slot reuse. MLP is HW-queue-deep, VGPR-free.

#define NB      20
#define BLK     256      // 4 waves
#define GRID_H  1024
#define PSTRIDE 64       // padded row per block in workspace

// 16B-per-lane DMA: LDS dest = wave-uniform base + lane*16 (m97/m104).
__device__ __forceinline__ void dma16(const void* g, void* l) {
    __builtin_amdgcn_global_load_lds(
        (const __attribute__((address_space(1))) unsigned*)g,
        (__attribute__((address_space(3))) unsigned*)l, 16, 0, 0);
}

__device__ __forceinline__ void process_pix(int p, int t, unsigned* s_col) {
    // packed fields: bits 0..9 pred_count, 10..19 target_count, 20..29 inter
    unsigned m = (unsigned)(p == t);
    atomicAdd(&s_col[p * BLK], 1u + (m << 20));  // pred count + intersection
    atomicAdd(&s_col[t * BLK], 1u << 10);        // target count
}

__device__ __forceinline__ void process_vec(int4 pv, int4 tv, unsigned* s_col) {
    process_pix(pv.x, tv.x, s_col);
    process_pix(pv.y, tv.y, s_col);
    process_pix(pv.z, tv.z, s_col);
    process_pix(pv.w, tv.w, s_col);
}

__global__ __launch_bounds__(BLK) void miou_hist_kernel(
        const int4* __restrict__ preds, const int4* __restrict__ targs,
        unsigned* __restrict__ partials, int n4, int full_iters) {
    __shared__ unsigned s_hist[NB * BLK];   // 20KB
    __shared__ int4 s_p[2][BLK];            // 8KB: 2 slots x (4 waves x 64 int4)
    __shared__ int4 s_t[2][BLK];            // 8KB
    const int tid  = threadIdx.x;
    const int wid  = tid >> 6;
    const int lane = tid & 63;

    #pragma unroll
    for (int c = 0; c < NB; ++c) s_hist[c * BLK + tid] = 0u;
    __syncthreads();

    unsigned* s_col = &s_hist[tid];
    const int CHUNK = gridDim.x * BLK;          // int4s per grid-iteration
    const int base  = blockIdx.x * BLK + tid;   // this thread's lane-linear idx

    if (full_iters >= 2) {
        // Prologue: 2 slot-pairs in flight per wave (4 DMAs).
        dma16(&preds[base],         &s_p[0][wid * 64]);
        dma16(&targs[base],         &s_t[0][wid * 64]);
        dma16(&preds[base + CHUNK], &s_p[1][wid * 64]);
        dma16(&targs[base + CHUNK], &s_t[1][wid * 64]);

        for (int j = 0; j < full_iters - 1; ++j) {
            const int slot = j & 1;
            // Pair j complete when <=2 newer ops remain outstanding.
            asm volatile("s_waitcnt vmcnt(2)" ::: "memory");
            int4 pv = s_p[slot][wid * 64 + lane];   // ds_read_b128
            int4 tv = s_t[slot][wid * 64 + lane];
            // Reads must land before the DMA below overwrites the slot.
            asm volatile("s_waitcnt lgkmcnt(0)" ::: "memory");
            if (j + 2 < full_iters) {
                dma16(&preds[base + (j + 2) * CHUNK], &s_p[slot][wid * 64]);
                dma16(&targs[base + (j + 2) * CHUNK], &s_t[slot][wid * 64]);
            }
            process_vec(pv, tv, s_col);
        }
        {   // Final iteration: drain.
            const int slot = (full_iters - 1) & 1;
            asm volatile("s_waitcnt vmcnt(0)" ::: "memory");
            int4 pv = s_p[slot][wid * 64 + lane];
            int4 tv = s_t[slot][wid * 64 + lane];
            process_vec(pv, tv, s_col);
        }
    }
    // Tail (empty for the bench shape; also covers full_iters<2).
    for (int i = base + full_iters * CHUNK; i < n4; i += CHUNK) {
        int4 pv = preds[i];
        int4 tv = targs[i];
        process_vec(pv, tv, s_col);
    }
    __syncthreads();

    // Block reduction: 4 waves, wave w handles classes w, w+4, ..., <NB.
    unsigned* dst = &partials[(size_t)blockIdx.x * PSTRIDE];
    for (int c = wid; c < NB; c += (BLK / 64)) {
        unsigned sp = 0, st = 0, si = 0;
        #pragma unroll
        for (int k = 0; k < BLK / 64; ++k) {
            unsigned v = s_hist[c * BLK + k * 64 + lane];
            sp += v & 1023u;
            st += (v >> 10) & 1023u;
            si += (v >> 20) & 1023u;
        }
        #pragma unroll
        for (int off = 32; off > 0; off >>= 1) {
            sp += __shfl_xor(sp, off);
            st += __shfl_xor(st, off);
            si += __shfl_xor(si, off);
        }
        if (lane == 0) {
            dst[c]          = sp;
            dst[NB + c]     = st;
            dst[2 * NB + c] = si;
        }
    }
}

// One block, 1024 threads. partials = nblocks rows x 16 int4 (coalesced).
__global__ __launch_bounds__(1024) void miou_reduce_kernel(
        const unsigned* __restrict__ partials, int nblocks,
        const int* __restrict__ nb_ptr, const int* __restrict__ smooth_ptr,
        float* __restrict__ out) {
    __shared__ unsigned s_tot[PSTRIDE];
    if (threadIdx.x < PSTRIDE) s_tot[threadIdx.x] = 0u;
    __syncthreads();

    const int col4 = threadIdx.x & 15;
    const int seg  = threadIdx.x >> 4;
    const int4* p4 = (const int4*)partials;

    unsigned ax = 0, ay = 0, az = 0, aw = 0;
    #pragma unroll 8
    for (int r = seg; r < nblocks; r += 64) {
        int4 v = p4[r * 16 + col4];
        ax += (unsigned)v.x; ay += (unsigned)v.y;
        az += (unsigned)v.z; aw += (unsigned)v.w;
    }
    atomicAdd(&s_tot[col4 * 4 + 0], ax);
    atomicAdd(&s_tot[col4 * 4 + 1], ay);
    atomicAdd(&s_tot[col4 * 4 + 2], az);
    atomicAdd(&s_tot[col4 * 4 + 3], aw);
    __syncthreads();

    if (threadIdx.x == 0) {
        const int   nb = *nb_ptr;
        const float s  = (float)(*smooth_ptr);
        float acc_iou = 0.0f;
        for (int c = 0; c < nb && c < NB; ++c) {
            float pc    = (float)s_tot[c];
            float tc    = (float)s_tot[NB + c];
            float inter = (float)s_tot[2 * NB + c];
            float uni   = pc + tc - inter;
            acc_iou += (inter + s) / (uni + s);
        }
        out[0] = 1.0f - acc_iou / (float)nb;
    }
}

extern "C" void kernel_launch(void* const* d_in, const int* in_sizes, int n_in,
                              void* d_out, int out_size, void* d_ws, size_t ws_size,
                              hipStream_t stream) {
    const int4* preds      = (const int4*)d_in[0];
    const int4* targs      = (const int4*)d_in[1];
    const int*  nb_ptr     = (const int*)d_in[2];
    const int*  smooth_ptr = (const int*)d_in[3];
    float*      out        = (float*)d_out;

    int n  = in_sizes[0];
    int n4 = n >> 2;  // 16M pixels, divisible by 4

    unsigned* partials = (unsigned*)d_ws;

    int grid = GRID_H;
    int max_grid = (n4 + BLK - 1) / BLK;
    if (grid > max_grid) grid = max_grid;
    size_t need_per_block = PSTRIDE * sizeof(unsigned);
    if ((size_t)grid * need_per_block > ws_size)
        grid = (int)(ws_size / need_per_block);

    int chunk = grid * BLK;
    int full  = n4 / chunk;
    if (full < 2) full = 0;   // tiny shapes -> tail path handles everything

    miou_hist_kernel<<<grid, BLK, 0, stream>>>(preds, targs, partials, n4, full);
    miou_reduce_kernel<<<1, 1024, 0, stream>>>(partials, grid, nb_ptr, smooth_ptr, out);
}

// Round 9
// 32.688 us; speedup vs baseline: 1.9834x; 1.0593x over previous
//
#include <hip/hip_runtime.h>
#include <hip/hip_bf16.h>

// mIoU loss, pair-key histogram formulation, two-stage (no global atomics).
// Ledger:
//  R1: global atomics on 60 addrs -> 313us (serialized far-atomics).
//  R2~R3: 4 plain DS ops/px vs 2 DS atomics/px identical 42us ->
//         CONSISTENT with DS-pipe-bound at atomic ~2x plain cost
//         (mis-read at the time as "DS exonerated").
//  R4~R6: VGPR-liveness idioms all failed (VGPR 28/36/44); allocator wins.
//  R7 ablation: load-only probe ~27us -> load path ALSO broken pre-DMA.
//  R8: global_load_lds DMA double-buffer, counted vmcnt(2): loads fixed,
//      wall ~unmoved -> DS-atomic pipe indicted (~2048 wave-atomics/CU
//      at ~25-35cy explains the invariant ~30us).
//  R9: HALVE atomics: pair-key hist (key=p*20+t, ONE ds_add per pixel,
//      400 keys x 32 copies = 50KB, conflict-free). Marginals recover
//      pred/target/inter. DMA load path kept from R8.

#define NB      20
#define NKEY    (NB * NB)   // 400
#define NCOPY   32
#define BLK     256         // 4 waves
#define GRID_H  512         // exactly 2 blocks/CU resident
#define PSTRIDE 64          // padded row per block in workspace

// 16B-per-lane DMA: LDS dest = wave-uniform base + lane*16 (m97/m104).
__device__ __forceinline__ void dma16(const void* g, void* l) {
    __builtin_amdgcn_global_load_lds(
        (const __attribute__((address_space(1))) unsigned*)g,
        (__attribute__((address_space(3))) unsigned*)l, 16, 0, 0);
}

__device__ __forceinline__ void process_pix(int p, int t, unsigned* hist_cp) {
    // ONE fire-and-forget LDS atomic per pixel. hist_cp = &s_hist[copy].
    atomicAdd(&hist_cp[(p * NB + t) * NCOPY], 1u);
}

__device__ __forceinline__ void process_vec(int4 pv, int4 tv, unsigned* hist_cp) {
    process_pix(pv.x, tv.x, hist_cp);
    process_pix(pv.y, tv.y, hist_cp);
    process_pix(pv.z, tv.z, hist_cp);
    process_pix(pv.w, tv.w, hist_cp);
}

__global__ __launch_bounds__(BLK) void miou_hist_kernel(
        const int4* __restrict__ preds, const int4* __restrict__ targs,
        unsigned* __restrict__ partials, int n4, int full_iters) {
    __shared__ unsigned s_hist[NKEY * NCOPY];   // 50 KB
    __shared__ int4 s_p[2][BLK];                // 8 KB staging (2 slots)
    __shared__ int4 s_t[2][BLK];                // 8 KB
    const int tid  = threadIdx.x;
    const int wid  = tid >> 6;
    const int lane = tid & 63;

    for (int k = tid; k < NKEY * NCOPY; k += BLK) s_hist[k] = 0u;
    __syncthreads();

    unsigned* hist_cp = &s_hist[tid & (NCOPY - 1)];
    const int CHUNK = gridDim.x * BLK;          // int4s per grid-iteration
    const int base  = blockIdx.x * BLK + tid;

    if (full_iters >= 2) {
        // Prologue: 2 slot-pairs in flight per wave (4 DMAs outstanding).
        dma16(&preds[base],         &s_p[0][wid * 64]);
        dma16(&targs[base],         &s_t[0][wid * 64]);
        dma16(&preds[base + CHUNK], &s_p[1][wid * 64]);
        dma16(&targs[base + CHUNK], &s_t[1][wid * 64]);

        for (int j = 0; j < full_iters - 1; ++j) {
            const int slot = j & 1;
            // Pair j landed when <=2 newer DMAs remain outstanding.
            asm volatile("s_waitcnt vmcnt(2)" ::: "memory");
            int4 pv = s_p[slot][wid * 64 + lane];   // ds_read_b128
            int4 tv = s_t[slot][wid * 64 + lane];
            // Reads (and prior atomics) drain before slot overwrite.
            asm volatile("s_waitcnt lgkmcnt(0)" ::: "memory");
            if (j + 2 < full_iters) {
                dma16(&preds[base + (j + 2) * CHUNK], &s_p[slot][wid * 64]);
                dma16(&targs[base + (j + 2) * CHUNK], &s_t[slot][wid * 64]);
            }
            process_vec(pv, tv, hist_cp);
        }
        {   // Final iteration: drain.
            const int slot = (full_iters - 1) & 1;
            asm volatile("s_waitcnt vmcnt(0)" ::: "memory");
            int4 pv = s_p[slot][wid * 64 + lane];
            int4 tv = s_t[slot][wid * 64 + lane];
            process_vec(pv, tv, hist_cp);
        }
    }
    // Tail (empty for the bench shape; also covers full_iters<2).
    for (int i = base + full_iters * CHUNK; i < n4; i += CHUNK) {
        int4 pv = preds[i];
        int4 tv = targs[i];
        process_vec(pv, tv, hist_cp);
    }
    __syncthreads();

    // Marginal reduction: wave w handles classes w, w+4, ..., <NB.
    //  pc[c] = sum over 640 contiguous words [c*640, c*640+640)
    //  tc[c] = sum over p of words p*640 + c*32 + copy   (bank = copy: clean)
    //  ic[c] = 32 copies of key c*21
    unsigned* dst = &partials[(size_t)blockIdx.x * PSTRIDE];
    for (int c = wid; c < NB; c += (BLK / 64)) {
        unsigned pcs = 0;
        #pragma unroll
        for (int k = 0; k < 640; k += 64) pcs += s_hist[c * 640 + k + lane];

        unsigned tcs = 0;
        {
            const int copy = lane & 31;
            const int p0   = lane >> 5;   // 0 or 1
            #pragma unroll
            for (int p = 0; p < NB; p += 2)
                tcs += s_hist[(p + p0) * 640 + c * 32 + copy];
        }
        unsigned ics = (lane < 32) ? s_hist[c * 21 * 32 + lane] : 0u;

        #pragma unroll
        for (int off = 32; off > 0; off >>= 1) {
            pcs += __shfl_xor(pcs, off);
            tcs += __shfl_xor(tcs, off);
            ics += __shfl_xor(ics, off);
        }
        if (lane == 0) {
            dst[c]          = pcs;
            dst[NB + c]     = tcs;
            dst[2 * NB + c] = ics;
        }
    }
}

// One block, 1024 threads. partials = nblocks rows x 16 int4 (coalesced).
__global__ __launch_bounds__(1024) void miou_reduce_kernel(
        const unsigned* __restrict__ partials, int nblocks,
        const int* __restrict__ nb_ptr, const int* __restrict__ smooth_ptr,
        float* __restrict__ out) {
    __shared__ unsigned s_tot[PSTRIDE];
    if (threadIdx.x < PSTRIDE) s_tot[threadIdx.x] = 0u;
    __syncthreads();

    const int col4 = threadIdx.x & 15;
    const int seg  = threadIdx.x >> 4;
    const int4* p4 = (const int4*)partials;

    unsigned ax = 0, ay = 0, az = 0, aw = 0;
    #pragma unroll 8
    for (int r = seg; r < nblocks; r += 64) {
        int4 v = p4[r * 16 + col4];
        ax += (unsigned)v.x; ay += (unsigned)v.y;
        az += (unsigned)v.z; aw += (unsigned)v.w;
    }
    atomicAdd(&s_tot[col4 * 4 + 0], ax);
    atomicAdd(&s_tot[col4 * 4 + 1], ay);
    atomicAdd(&s_tot[col4 * 4 + 2], az);
    atomicAdd(&s_tot[col4 * 4 + 3], aw);
    __syncthreads();

    if (threadIdx.x == 0) {
        const int   nb = *nb_ptr;
        const float s  = (float)(*smooth_ptr);
        float acc_iou = 0.0f;
        for (int c = 0; c < nb && c < NB; ++c) {
            float pc    = (float)s_tot[c];
            float tc    = (float)s_tot[NB + c];
            float inter = (float)s_tot[2 * NB + c];
            float uni   = pc + tc - inter;
            acc_iou += (inter + s) / (uni + s);
        }
        out[0] = 1.0f - acc_iou / (float)nb;
    }
}

extern "C" void kernel_launch(void* const* d_in, const int* in_sizes, int n_in,
                              void* d_out, int out_size, void* d_ws, size_t ws_size,
                              hipStream_t stream) {
    const int4* preds      = (const int4*)d_in[0];
    const int4* targs      = (const int4*)d_in[1];
    const int*  nb_ptr     = (const int*)d_in[2];
    const int*  smooth_ptr = (const int*)d_in[3];
    float*      out        = (float*)d_out;

    int n  = in_sizes[0];
    int n4 = n >> 2;  // 16M pixels, divisible by 4

    unsigned* partials = (unsigned*)d_ws;

    int grid = GRID_H;
    int max_grid = (n4 + BLK - 1) / BLK;
    if (grid > max_grid) grid = max_grid;
    size_t need_per_block = PSTRIDE * sizeof(unsigned);
    if ((size_t)grid * need_per_block > ws_size)
        grid = (int)(ws_size / need_per_block);

    int chunk = grid * BLK;
    int full  = (chunk > 0) ? (n4 / chunk) : 0;
    if (full < 2) full = 0;   // tiny shapes -> tail path handles everything

    miou_hist_kernel<<<grid, BLK, 0, stream>>>(preds, targs, partials, n4, full);
    miou_reduce_kernel<<<1, 1024, 0, stream>>>(partials, grid, nb_ptr, smooth_ptr, out);
}